// Round 3
// baseline (109.008 us; speedup 1.0000x reference)
//
#include <hip/hip_runtime.h>

// LIF SNN, 50 timesteps x 8192 neurons.
// 1) prep:          x f32 -> bf16 (padded to 64 t), zero FF + spike flag
// 2) ff_gemm_mfma:  FF[t][j] = sum_k x[t][k]*w_in[j][k] via bf16 MFMA.
//                   W tile staged through LDS with coalesced 128B-segment
//                   global loads, double-buffered, XOR-16B swizzle (T2) on
//                   LDS reads; f32->bf16 cvt in-register; K-split 16 with
//                   f32 atomicAdd into FF.
// 3) spec_scan:     per-neuron parallel scan assuming no spikes (true here:
//                   threshold margin ~15 units); all 50 FF values prefetched
//                   to registers; flags if any spike occurred
// 4) lif_fallback:  exact sequential event-driven scan, runs only if flagged

#define NEUR 8192
#define TSTEPS 50
#define TPAD 64

typedef __attribute__((ext_vector_type(8))) short bs8;   // 8 bf16 (4 VGPR)
typedef __attribute__((ext_vector_type(4))) float fx4;   // MFMA C/D

static __device__ __forceinline__ unsigned short f2b(float f) {
    // f32 -> bf16 round-to-nearest-even
    unsigned u = __float_as_uint(f);
    return (unsigned short)((u + 0x7FFFu + ((u >> 16) & 1u)) >> 16);
}

// ---------------- K0: convert x, zero FF + flag ----------------
__global__ __launch_bounds__(256)
void prep(const float* __restrict__ x, unsigned short* __restrict__ xb,
          float* __restrict__ FF, int* __restrict__ flag)
{
    const int e = blockIdx.x * 256 + threadIdx.x;    // < TPAD*NEUR
    const int t = e >> 13;
    xb[e] = (t < TSTEPS) ? f2b(x[e]) : (unsigned short)0;
    if (e < TSTEPS * NEUR) FF[e] = 0.f;
    if (e == 0) *flag = 0;
}

// ---------------- K1: feed-forward GEMM via bf16 MFMA, LDS-staged W ----------------
// grid = 64 j-blocks (128 j) x 16 k-splits; block = 4 waves.
// Per block: 128 j x 512 k, BK=32 double-buffered (2 x 16 KB LDS).
#define KSPLIT 16
#define KCHUNK (NEUR / KSPLIT)    // 512
#define BK 32
#define NSTEP (KCHUNK / BK)       // 16

__global__ __launch_bounds__(256)
void ff_gemm_mfma(const float* __restrict__ w,            // [8192][8192]
                  const unsigned short* __restrict__ xb,  // [64][8192] bf16 bits
                  float* __restrict__ FF)                 // [50][8192]
{
    __shared__ float Wl[2 * 128 * BK];                    // 32 KB
    char* const smem = (char*)Wl;

    const int tid  = threadIdx.x;
    const int wv   = tid >> 6;
    const int lane = tid & 63;
    const int jb   = blockIdx.x & 63;     // 64 j-blocks
    const int ks   = blockIdx.x >> 6;     // 16 k-splits
    const int j0   = jb * 128;
    const int k0   = ks * KCHUNK;
    const int lrow = lane & 15;           // free-dim index within fragment
    const int lgrp = lane >> 4;           // k-group (0..3), 8 k each

    // staging map: flat f = it*256+tid -> row = f>>3 (32 f32/row), col16 = f&7
    const int fr = tid >> 3;              // 0..31
    const int fc = tid & 7;               // float4 index within row

    fx4 acc[2][4];
#pragma unroll
    for (int jt = 0; jt < 2; ++jt)
#pragma unroll
        for (int tb = 0; tb < 4; ++tb)
            acc[jt][tb] = (fx4){0.f, 0.f, 0.f, 0.f};

    float4 st[4];
    const float* const wbase = w + (size_t)j0 * NEUR + k0;

    auto LOADT = [&](int s) {             // coalesced: 8 rows x 128B per instr
        const float* wp = wbase + s * BK;
#pragma unroll
        for (int it = 0; it < 4; ++it)
            st[it] = *(const float4*)(wp + (size_t)(it * 32 + fr) * NEUR + fc * 4);
    };
    auto WRITET = [&](int buf) {          // swizzled LDS write (16B XOR)
        char* b = smem + buf * 16384;
#pragma unroll
        for (int it = 0; it < 4; ++it) {
            const int r = it * 32 + fr;
            *(float4*)(b + r * 128 + ((fc * 16) ^ ((r & 7) << 4))) = st[it];
        }
    };

    LOADT(0);
    WRITET(0);
    __syncthreads();

    const unsigned short* const xpk = xb + (size_t)lrow * NEUR + k0 + lgrp * 8;

    for (int s = 0; s < NSTEP; ++s) {
        if (s + 1 < NSTEP) LOADT(s + 1);  // prefetch next tile into regs

        // A fragments: 4 t-blocks of 16, lane reads 8 contiguous bf16 (L2-hot)
        const unsigned short* xp = xpk + s * BK;
        const bs8 a0 = *(const bs8*)(xp);
        const bs8 a1 = *(const bs8*)(xp + (size_t)16 * NEUR);
        const bs8 a2 = *(const bs8*)(xp + (size_t)32 * NEUR);
        const bs8 a3 = *(const bs8*)(xp + (size_t)48 * NEUR);

        // B fragments from swizzled LDS, f32 -> bf16 in-register
        char* const bb = smem + (s & 1) * 16384;
        bs8 bf[2];
#pragma unroll
        for (int jt = 0; jt < 2; ++jt) {
            const int row = wv * 32 + jt * 16 + lrow;
            const int sw  = (row & 7) << 4;
            const float4 lo = *(const float4*)(bb + row * 128 + ((lgrp * 32)      ^ sw));
            const float4 hi = *(const float4*)(bb + row * 128 + ((lgrp * 32 + 16) ^ sw));
            bf[jt] = (bs8){(short)f2b(lo.x), (short)f2b(lo.y), (short)f2b(lo.z), (short)f2b(lo.w),
                           (short)f2b(hi.x), (short)f2b(hi.y), (short)f2b(hi.z), (short)f2b(hi.w)};
        }

        acc[0][0] = __builtin_amdgcn_mfma_f32_16x16x32_bf16(a0, bf[0], acc[0][0], 0, 0, 0);
        acc[0][1] = __builtin_amdgcn_mfma_f32_16x16x32_bf16(a1, bf[0], acc[0][1], 0, 0, 0);
        acc[0][2] = __builtin_amdgcn_mfma_f32_16x16x32_bf16(a2, bf[0], acc[0][2], 0, 0, 0);
        acc[0][3] = __builtin_amdgcn_mfma_f32_16x16x32_bf16(a3, bf[0], acc[0][3], 0, 0, 0);
        acc[1][0] = __builtin_amdgcn_mfma_f32_16x16x32_bf16(a0, bf[1], acc[1][0], 0, 0, 0);
        acc[1][1] = __builtin_amdgcn_mfma_f32_16x16x32_bf16(a1, bf[1], acc[1][1], 0, 0, 0);
        acc[1][2] = __builtin_amdgcn_mfma_f32_16x16x32_bf16(a2, bf[1], acc[1][2], 0, 0, 0);
        acc[1][3] = __builtin_amdgcn_mfma_f32_16x16x32_bf16(a3, bf[1], acc[1][3], 0, 0, 0);

        if (s + 1 < NSTEP) {
            WRITET((s + 1) & 1);          // other buffer; nobody reads it now
            __syncthreads();              // one barrier/step keeps waves in lockstep
        }
    }

    // epilogue: C/D layout col = lane&15, row = (lane>>4)*4 + reg (HW-verified r2)
#pragma unroll
    for (int jt = 0; jt < 2; ++jt) {
        const int j = j0 + wv * 32 + jt * 16 + lrow;
#pragma unroll
        for (int tb = 0; tb < 4; ++tb)
#pragma unroll
            for (int i = 0; i < 4; ++i) {
                const int t = tb * 16 + lgrp * 4 + i;
                if (t < TSTEPS)
                    atomicAdd(&FF[(size_t)t * NEUR + j], acc[jt][tb][i]);
            }
    }
}

// ---------------- K2: speculative parallel scan (assumes z == 0) ----------------
__global__ __launch_bounds__(256)
void spec_scan(const float* __restrict__ FF, float* __restrict__ out,
               int* __restrict__ flag)
{
    const int j = blockIdx.x * 256 + threadIdx.x;   // one neuron per thread
    float ff[TSTEPS];                               // full prefetch, static idx
#pragma unroll
    for (int t = 0; t < TSTEPS; ++t) ff[t] = FF[(size_t)t * NEUR + j];

    float v = -70.f, cur = 0.f;
    bool any = false;
#pragma unroll
    for (int t = 0; t < TSTEPS; ++t) {
        const float vd = v + 5.0e-5f * ((-70.f - v) + cur);
        const float id = cur - 1.0e-4f * cur;
        const bool sp = vd > -55.f;
        any |= sp;
        v = sp ? -70.f : vd;
        cur = id + ff[t];                           // no recurrence (speculation)
        out[(size_t)t * NEUR + j] = sp ? 1.f : 0.f;
    }
    if (any) atomicAdd(flag, 1);
}

// ---------------- K3: exact event-driven fallback (only if spikes occurred) ----------------
__global__ __launch_bounds__(1024)
void lif_fallback(const float* __restrict__ FF, const float* __restrict__ wrec,
                  float* __restrict__ out, const int* __restrict__ flag)
{
    if (*flag == 0) return;   // speculation was self-consistent -> out is exact

    const int tid = threadIdx.x;
    __shared__ unsigned short list[2][NEUR];
    __shared__ int cnt[2];

    float v[8], cur[8];
#pragma unroll
    for (int n = 0; n < 8; ++n) { v[n] = -70.0f; cur[n] = 0.0f; }
    if (tid == 0) { cnt[0] = 0; cnt[1] = 0; }

    for (int t = 0; t < TSTEPS; ++t) {
        const int rb = t & 1, wb = rb ^ 1;
        __syncthreads();
        if (tid == 0) cnt[wb] = 0;
        __syncthreads();

        float rec[8];
#pragma unroll
        for (int n = 0; n < 8; ++n) rec[n] = 0.0f;
        const int c = cnt[rb];
        for (int s = 0; s < c; ++s) {
            const int k = list[rb][s];
#pragma unroll
            for (int n = 0; n < 8; ++n)
                rec[n] += wrec[(size_t)(tid + n * 1024) * NEUR + k];
        }

#pragma unroll
        for (int n = 0; n < 8; ++n) {
            const float ff = FF[(size_t)t * NEUR + tid + n * 1024];
            const float vd = v[n] + 5.0e-5f * ((-70.0f - v[n]) + cur[n]);
            const float id = cur[n] - 1.0e-4f * cur[n];
            const bool  sp = vd > -55.0f;
            v[n]   = sp ? -70.0f : vd;
            cur[n] = id + ff + rec[n];
            out[(size_t)t * NEUR + tid + n * 1024] = sp ? 1.0f : 0.0f;
            if (sp) {
                const int pos = atomicAdd(&cnt[wb], 1);
                list[wb][pos] = (unsigned short)(tid + n * 1024);
            }
        }
    }
}

extern "C" void kernel_launch(void* const* d_in, const int* in_sizes, int n_in,
                              void* d_out, int out_size, void* d_ws, size_t ws_size,
                              hipStream_t stream) {
    const float* x     = (const float*)d_in[0];   // [50][8192]
    const float* w_in  = (const float*)d_in[1];   // [8192][8192]
    const float* w_rec = (const float*)d_in[2];   // [8192][8192]
    float* out = (float*)d_out;

    // ws layout (16B-aligned): FF f32 [50][8192] | xb bf16 [64][8192] | flag
    float* FF = (float*)d_ws;
    unsigned short* xb = (unsigned short*)((char*)d_ws + (size_t)TSTEPS * NEUR * 4);
    int* flag = (int*)((char*)d_ws + (size_t)TSTEPS * NEUR * 4 + (size_t)TPAD * NEUR * 2);

    prep        <<<dim3(TPAD * NEUR / 256), dim3(256), 0, stream>>>(x, xb, FF, flag);
    ff_gemm_mfma<<<dim3(64 * KSPLIT),       dim3(256), 0, stream>>>(w_in, xb, FF);
    spec_scan   <<<dim3(NEUR / 256),        dim3(256), 0, stream>>>(FF, out, flag);
    lif_fallback<<<dim3(1),                 dim3(1024), 0, stream>>>(FF, w_rec, out, flag);
}

// Round 4
// 87.907 us; speedup vs baseline: 1.2400x; 1.2400x over previous
//
#include <hip/hip_runtime.h>

// LIF SNN, 50 timesteps x 8192 neurons.
// 1) prep:          x f32 -> bf16 (padded to 64 t), zero spike flag
// 2) ff_gemm_mfma:  FF partials[ks][t][j] = sum_{k in chunk} x[t][k]*w_in[j][k]
//                   via bf16 MFMA; w_in streamed f32 direct-to-fragment
//                   (no LDS, no atomics); partials stored as bf16.
// 3) reduce_ff:     FF = sum of 16 bf16 partials (f32 accumulate)
// 4) spec_scan:     per-neuron parallel scan assuming no spikes (true here:
//                   threshold margin ~15 units); 50 FF values prefetched to
//                   registers; flags if any spike occurred
// 5) lif_fallback:  exact sequential event-driven scan, runs only if flagged

#define NEUR 8192
#define TSTEPS 50
#define TPAD 64

typedef __attribute__((ext_vector_type(8))) short bs8;   // 8 bf16 (4 VGPR)
typedef __attribute__((ext_vector_type(4))) float fx4;   // MFMA C/D

static __device__ __forceinline__ unsigned short f2b(float f) {
    // f32 -> bf16 round-to-nearest-even
    unsigned u = __float_as_uint(f);
    return (unsigned short)((u + 0x7FFFu + ((u >> 16) & 1u)) >> 16);
}
static __device__ __forceinline__ float b2f(unsigned short b) {
    return __uint_as_float(((unsigned)b) << 16);
}

// ---------------- K0: convert x, zero flag ----------------
__global__ __launch_bounds__(256)
void prep(const float* __restrict__ x, unsigned short* __restrict__ xb,
          int* __restrict__ flag)
{
    const int e = blockIdx.x * 256 + threadIdx.x;    // < TPAD*NEUR
    const int t = e >> 13;
    xb[e] = (t < TSTEPS) ? f2b(x[e]) : (unsigned short)0;
    if (e == 0) *flag = 0;
}

// ---------------- K1: feed-forward GEMM via bf16 MFMA (r2 structure) ----------------
// grid = 64 j-blocks (128 j each) x 16 k-splits; block = 4 waves.
// wave -> 32 j (2 MFMA col-tiles) x 64 t x 512 k. Epilogue: plain bf16 stores.
#define KSPLIT 16
#define KCHUNK (NEUR / KSPLIT)    // 512
#define NKSTEP (KCHUNK / 32)      // 16

__global__ __launch_bounds__(256)
void ff_gemm_mfma(const float* __restrict__ w,            // [8192][8192]
                  const unsigned short* __restrict__ xb,  // [64][8192] bf16 bits
                  unsigned short* __restrict__ P)         // [KSPLIT][50][8192] bf16
{
    const int wv   = threadIdx.x >> 6;
    const int lane = threadIdx.x & 63;
    const int jb   = blockIdx.x & 63;     // 64 j-blocks
    const int ks   = blockIdx.x >> 6;     // 16 k-splits
    const int j0   = jb * 128 + wv * 32;
    const int k0   = ks * KCHUNK;
    const int lrow = lane & 15;           // free-dim index within fragment
    const int lgrp = lane >> 4;           // k-group (0..3), 8 k each

    fx4 acc[2][4];
#pragma unroll
    for (int jt = 0; jt < 2; ++jt)
#pragma unroll
        for (int tb = 0; tb < 4; ++tb)
            acc[jt][tb] = (fx4){0.f, 0.f, 0.f, 0.f};

    const unsigned short* xp = xb + (size_t)lrow * NEUR + k0 + lgrp * 8;
    const float* wpa = w + (size_t)(j0 + lrow) * NEUR + k0 + lgrp * 8;
    const float* wpb = wpa + (size_t)16 * NEUR;

#pragma unroll 2
    for (int kk = 0; kk < NKSTEP; ++kk) {
        const int ko = kk * 32;
        // A fragments: 4 t-blocks of 16, each lane 8 contiguous bf16 (16 B, L2-hot)
        const bs8 a0 = *(const bs8*)(xp + ko);
        const bs8 a1 = *(const bs8*)(xp + (size_t)16 * NEUR + ko);
        const bs8 a2 = *(const bs8*)(xp + (size_t)32 * NEUR + ko);
        const bs8 a3 = *(const bs8*)(xp + (size_t)48 * NEUR + ko);
        // B fragments: 2 j-tiles, each lane 8 contiguous f32 (32 B), cvt->bf16
        const float4 wa0 = *(const float4*)(wpa + ko);
        const float4 wa1 = *(const float4*)(wpa + ko + 4);
        const float4 wb0 = *(const float4*)(wpb + ko);
        const float4 wb1 = *(const float4*)(wpb + ko + 4);
        const bs8 b0 = {(short)f2b(wa0.x), (short)f2b(wa0.y), (short)f2b(wa0.z), (short)f2b(wa0.w),
                        (short)f2b(wa1.x), (short)f2b(wa1.y), (short)f2b(wa1.z), (short)f2b(wa1.w)};
        const bs8 b1 = {(short)f2b(wb0.x), (short)f2b(wb0.y), (short)f2b(wb0.z), (short)f2b(wb0.w),
                        (short)f2b(wb1.x), (short)f2b(wb1.y), (short)f2b(wb1.z), (short)f2b(wb1.w)};

        acc[0][0] = __builtin_amdgcn_mfma_f32_16x16x32_bf16(a0, b0, acc[0][0], 0, 0, 0);
        acc[0][1] = __builtin_amdgcn_mfma_f32_16x16x32_bf16(a1, b0, acc[0][1], 0, 0, 0);
        acc[0][2] = __builtin_amdgcn_mfma_f32_16x16x32_bf16(a2, b0, acc[0][2], 0, 0, 0);
        acc[0][3] = __builtin_amdgcn_mfma_f32_16x16x32_bf16(a3, b0, acc[0][3], 0, 0, 0);
        acc[1][0] = __builtin_amdgcn_mfma_f32_16x16x32_bf16(a0, b1, acc[1][0], 0, 0, 0);
        acc[1][1] = __builtin_amdgcn_mfma_f32_16x16x32_bf16(a1, b1, acc[1][1], 0, 0, 0);
        acc[1][2] = __builtin_amdgcn_mfma_f32_16x16x32_bf16(a2, b1, acc[1][2], 0, 0, 0);
        acc[1][3] = __builtin_amdgcn_mfma_f32_16x16x32_bf16(a3, b1, acc[1][3], 0, 0, 0);
    }

    // epilogue: C/D layout col = lane&15, row = (lane>>4)*4 + reg.
    // Plain bf16 stores into this k-split's partial plane (no contention).
#pragma unroll
    for (int jt = 0; jt < 2; ++jt) {
        const int j = j0 + jt * 16 + lrow;
#pragma unroll
        for (int tb = 0; tb < 4; ++tb)
#pragma unroll
            for (int i = 0; i < 4; ++i) {
                const int t = tb * 16 + lgrp * 4 + i;
                if (t < TSTEPS)
                    P[((size_t)ks * TSTEPS + t) * NEUR + j] = f2b(acc[jt][tb][i]);
            }
    }
}

// ---------------- K2: reduce bf16 partials -> FF f32 ----------------
typedef __attribute__((ext_vector_type(8))) unsigned short us8;

__global__ __launch_bounds__(256)
void reduce_ff(const unsigned short* __restrict__ P, float* __restrict__ FF)
{
    const int i = (blockIdx.x * 256 + threadIdx.x) * 8;   // < 409600, 200 blocks
    float s[8];
#pragma unroll
    for (int n = 0; n < 8; ++n) s[n] = 0.f;
#pragma unroll
    for (int ks = 0; ks < KSPLIT; ++ks) {
        const us8 p = *(const us8*)&P[(size_t)ks * TSTEPS * NEUR + i];
#pragma unroll
        for (int n = 0; n < 8; ++n) s[n] += b2f(p[n]);
    }
    *(float4*)&FF[i]     = make_float4(s[0], s[1], s[2], s[3]);
    *(float4*)&FF[i + 4] = make_float4(s[4], s[5], s[6], s[7]);
}

// ---------------- K3: speculative parallel scan (assumes z == 0) ----------------
__global__ __launch_bounds__(256)
void spec_scan(const float* __restrict__ FF, float* __restrict__ out,
               int* __restrict__ flag)
{
    const int j = blockIdx.x * 256 + threadIdx.x;   // one neuron per thread
    float ff[TSTEPS];                               // full prefetch, static idx
#pragma unroll
    for (int t = 0; t < TSTEPS; ++t) ff[t] = FF[(size_t)t * NEUR + j];

    float v = -70.f, cur = 0.f;
    bool any = false;
#pragma unroll
    for (int t = 0; t < TSTEPS; ++t) {
        const float vd = v + 5.0e-5f * ((-70.f - v) + cur);
        const float id = cur - 1.0e-4f * cur;
        const bool sp = vd > -55.f;
        any |= sp;
        v = sp ? -70.f : vd;
        cur = id + ff[t];                           // no recurrence (speculation)
        out[(size_t)t * NEUR + j] = sp ? 1.f : 0.f;
    }
    if (any) atomicAdd(flag, 1);
}

// ---------------- K4: exact event-driven fallback (only if spikes occurred) ----------------
__global__ __launch_bounds__(1024)
void lif_fallback(const float* __restrict__ FF, const float* __restrict__ wrec,
                  float* __restrict__ out, const int* __restrict__ flag)
{
    if (*flag == 0) return;   // speculation was self-consistent -> out is exact

    const int tid = threadIdx.x;
    __shared__ unsigned short list[2][NEUR];
    __shared__ int cnt[2];

    float v[8], cur[8];
#pragma unroll
    for (int n = 0; n < 8; ++n) { v[n] = -70.0f; cur[n] = 0.0f; }
    if (tid == 0) { cnt[0] = 0; cnt[1] = 0; }

    for (int t = 0; t < TSTEPS; ++t) {
        const int rb = t & 1, wb = rb ^ 1;
        __syncthreads();
        if (tid == 0) cnt[wb] = 0;
        __syncthreads();

        float rec[8];
#pragma unroll
        for (int n = 0; n < 8; ++n) rec[n] = 0.0f;
        const int c = cnt[rb];
        for (int s = 0; s < c; ++s) {
            const int k = list[rb][s];
#pragma unroll
            for (int n = 0; n < 8; ++n)
                rec[n] += wrec[(size_t)(tid + n * 1024) * NEUR + k];
        }

#pragma unroll
        for (int n = 0; n < 8; ++n) {
            const float ff = FF[(size_t)t * NEUR + tid + n * 1024];
            const float vd = v[n] + 5.0e-5f * ((-70.0f - v[n]) + cur[n]);
            const float id = cur[n] - 1.0e-4f * cur[n];
            const bool  sp = vd > -55.0f;
            v[n]   = sp ? -70.0f : vd;
            cur[n] = id + ff + rec[n];
            out[(size_t)t * NEUR + tid + n * 1024] = sp ? 1.0f : 0.0f;
            if (sp) {
                const int pos = atomicAdd(&cnt[wb], 1);
                list[wb][pos] = (unsigned short)(tid + n * 1024);
            }
        }
    }
}

extern "C" void kernel_launch(void* const* d_in, const int* in_sizes, int n_in,
                              void* d_out, int out_size, void* d_ws, size_t ws_size,
                              hipStream_t stream) {
    const float* x     = (const float*)d_in[0];   // [50][8192]
    const float* w_in  = (const float*)d_in[1];   // [8192][8192]
    const float* w_rec = (const float*)d_in[2];   // [8192][8192]
    float* out = (float*)d_out;

    // ws layout (16B-aligned):
    //   FF  f32  [50][8192]          1,638,400 B  @ 0
    //   xb  bf16 [64][8192]          1,048,576 B  @ 1,638,400
    //   P   bf16 [16][50][8192]     13,107,200 B  @ 2,686,976
    //   flag int                            4 B  @ 15,794,176
    float* FF          = (float*)d_ws;
    unsigned short* xb = (unsigned short*)((char*)d_ws + 1638400);
    unsigned short* P  = (unsigned short*)((char*)d_ws + 2686976);
    int* flag          = (int*)((char*)d_ws + 15794176);

    prep        <<<dim3(TPAD * NEUR / 256),      dim3(256),  0, stream>>>(x, xb, flag);
    ff_gemm_mfma<<<dim3(64 * KSPLIT),            dim3(256),  0, stream>>>(w_in, xb, P);
    reduce_ff   <<<dim3(TSTEPS * NEUR / 8 / 256), dim3(256), 0, stream>>>(P, FF);
    spec_scan   <<<dim3(NEUR / 256),             dim3(256),  0, stream>>>(FF, out, flag);
    lif_fallback<<<dim3(1),                      dim3(1024), 0, stream>>>(FF, w_rec, out, flag);
}

// Round 5
// 83.309 us; speedup vs baseline: 1.3085x; 1.0552x over previous
//
#include <hip/hip_runtime.h>

// LIF SNN, 50 timesteps x 8192 neurons.
// 1) prep:          x f32 -> bf16 (padded to 64 t, vectorized), zero flag
// 2) ff_gemm_mfma:  P[ks][t][j] = sum_{k in chunk} x[t][k]*w_in[j][k] via bf16
//                   MFMA; w_in streamed f32 direct-to-fragment with an
//                   EXPLICIT 2-deep register pipeline (issue stage s+1's 8
//                   loads before consuming stage s -> vmcnt(8) waits, 16 KB
//                   in flight per wave). No LDS, no atomics. bf16 partials.
// 3) reduce_ff:     FF = sum of 16 bf16 partials (f32 accumulate)
// 4) spec_scan:     per-neuron scan assuming no spikes (threshold margin ~15
//                   units); 50 FF values prefetched; flags if any spike
// 5) lif_fallback:  exact sequential event-driven scan, runs only if flagged

#define NEUR 8192
#define TSTEPS 50
#define TPAD 64

typedef __attribute__((ext_vector_type(8))) short bs8;           // 8 bf16
typedef __attribute__((ext_vector_type(4))) float fx4;           // MFMA C/D
typedef __attribute__((ext_vector_type(8))) unsigned short us8;  // 8 bf16 bits

static __device__ __forceinline__ unsigned short f2b(float f) {
    // f32 -> bf16 round-to-nearest-even
    unsigned u = __float_as_uint(f);
    return (unsigned short)((u + 0x7FFFu + ((u >> 16) & 1u)) >> 16);
}
static __device__ __forceinline__ float b2f(unsigned short b) {
    return __uint_as_float(((unsigned)b) << 16);
}

// ---------------- K0: convert x (vectorized), zero flag ----------------
__global__ __launch_bounds__(256)
void prep(const float* __restrict__ x, unsigned short* __restrict__ xb,
          int* __restrict__ flag)
{
    const int e8 = blockIdx.x * 256 + threadIdx.x;   // < TPAD*NEUR/8 = 65536
    const int e  = e8 * 8;
    const int t  = e >> 13;
    us8 o;
    if (t < TSTEPS) {
        const float4 lo = *(const float4*)&x[e];
        const float4 hi = *(const float4*)&x[e + 4];
        o = (us8){f2b(lo.x), f2b(lo.y), f2b(lo.z), f2b(lo.w),
                  f2b(hi.x), f2b(hi.y), f2b(hi.z), f2b(hi.w)};
    } else {
        o = (us8){0, 0, 0, 0, 0, 0, 0, 0};
    }
    *(us8*)&xb[e] = o;
    if (e8 == 0) *flag = 0;
}

// ---------------- K1: feed-forward GEMM via bf16 MFMA, 2-deep pipeline ----------------
// grid = 64 j-blocks (128 j each) x 16 k-splits; block = 4 waves.
// wave -> 32 j (2 MFMA col-tiles) x 64 t x 512 k.
#define KSPLIT 16
#define KCHUNK (NEUR / KSPLIT)    // 512
#define NKSTEP (KCHUNK / 32)      // 16 (even -> pipeline epilogue is clean)

__global__ __launch_bounds__(256, 4)   // cap VGPR<=128: keep 4 blocks/CU resident
void ff_gemm_mfma(const float* __restrict__ w,            // [8192][8192]
                  const unsigned short* __restrict__ xb,  // [64][8192] bf16 bits
                  unsigned short* __restrict__ P)         // [KSPLIT][50][8192] bf16
{
    const int wv   = threadIdx.x >> 6;
    const int lane = threadIdx.x & 63;
    const int jb   = blockIdx.x & 63;     // 64 j-blocks
    const int ks   = blockIdx.x >> 6;     // 16 k-splits
    const int j0   = jb * 128 + wv * 32;
    const int k0   = ks * KCHUNK;
    const int lrow = lane & 15;           // free-dim index within fragment
    const int lgrp = lane >> 4;           // k-group (0..3), 8 k each

    fx4 acc[2][4];
#pragma unroll
    for (int jt = 0; jt < 2; ++jt)
#pragma unroll
        for (int tb = 0; tb < 4; ++tb)
            acc[jt][tb] = (fx4){0.f, 0.f, 0.f, 0.f};

    // loop-invariant base pointers; per-stage offsets are compile-time imms
    const unsigned short* const xp0 = xb + (size_t)lrow * NEUR + k0 + lgrp * 8;
    const unsigned short* const xp1 = xp0 + (size_t)16 * NEUR;
    const unsigned short* const xp2 = xp0 + (size_t)32 * NEUR;
    const unsigned short* const xp3 = xp0 + (size_t)48 * NEUR;
    const float* const wa = w + (size_t)(j0 + lrow) * NEUR + k0 + lgrp * 8;
    const float* const wb = wa + (size_t)16 * NEUR;

    // two named stage register sets (static indices only)
    bs8    A0[4], A1[4];
    float4 W0[4], W1[4];

#define LOADS(Aset, Wset, KO)                                   \
    do {                                                        \
        Aset[0] = *(const bs8*)(xp0 + (KO));                    \
        Aset[1] = *(const bs8*)(xp1 + (KO));                    \
        Aset[2] = *(const bs8*)(xp2 + (KO));                    \
        Aset[3] = *(const bs8*)(xp3 + (KO));                    \
        Wset[0] = *(const float4*)(wa + (KO));                  \
        Wset[1] = *(const float4*)(wa + (KO) + 4);              \
        Wset[2] = *(const float4*)(wb + (KO));                  \
        Wset[3] = *(const float4*)(wb + (KO) + 4);              \
    } while (0)

#define COMP(Aset, Wset)                                                        \
    do {                                                                        \
        const bs8 b0 = {(short)f2b(Wset[0].x), (short)f2b(Wset[0].y),           \
                        (short)f2b(Wset[0].z), (short)f2b(Wset[0].w),           \
                        (short)f2b(Wset[1].x), (short)f2b(Wset[1].y),           \
                        (short)f2b(Wset[1].z), (short)f2b(Wset[1].w)};          \
        const bs8 b1 = {(short)f2b(Wset[2].x), (short)f2b(Wset[2].y),           \
                        (short)f2b(Wset[2].z), (short)f2b(Wset[2].w),           \
                        (short)f2b(Wset[3].x), (short)f2b(Wset[3].y),           \
                        (short)f2b(Wset[3].z), (short)f2b(Wset[3].w)};          \
        acc[0][0] = __builtin_amdgcn_mfma_f32_16x16x32_bf16(Aset[0], b0, acc[0][0], 0, 0, 0); \
        acc[0][1] = __builtin_amdgcn_mfma_f32_16x16x32_bf16(Aset[1], b0, acc[0][1], 0, 0, 0); \
        acc[0][2] = __builtin_amdgcn_mfma_f32_16x16x32_bf16(Aset[2], b0, acc[0][2], 0, 0, 0); \
        acc[0][3] = __builtin_amdgcn_mfma_f32_16x16x32_bf16(Aset[3], b0, acc[0][3], 0, 0, 0); \
        acc[1][0] = __builtin_amdgcn_mfma_f32_16x16x32_bf16(Aset[0], b1, acc[1][0], 0, 0, 0); \
        acc[1][1] = __builtin_amdgcn_mfma_f32_16x16x32_bf16(Aset[1], b1, acc[1][1], 0, 0, 0); \
        acc[1][2] = __builtin_amdgcn_mfma_f32_16x16x32_bf16(Aset[2], b1, acc[1][2], 0, 0, 0); \
        acc[1][3] = __builtin_amdgcn_mfma_f32_16x16x32_bf16(Aset[3], b1, acc[1][3], 0, 0, 0); \
    } while (0)

    LOADS(A0, W0, 0);                       // prologue: stage 0 in flight
#pragma unroll 1
    for (int kk = 0; kk < NKSTEP; kk += 2) {
        if (kk + 1 < NKSTEP) LOADS(A1, W1, (kk + 1) * 32);  // issue next stage
        COMP(A0, W0);                       // waits vmcnt(8): stage-1 stays in flight
        if (kk + 2 < NKSTEP) LOADS(A0, W0, (kk + 2) * 32);
        COMP(A1, W1);
    }
#undef LOADS
#undef COMP

    // epilogue: C/D layout col = lane&15, row = (lane>>4)*4 + reg.
    // Plain bf16 stores into this k-split's partial plane.
#pragma unroll
    for (int jt = 0; jt < 2; ++jt) {
        const int j = j0 + jt * 16 + lrow;
#pragma unroll
        for (int tb = 0; tb < 4; ++tb)
#pragma unroll
            for (int i = 0; i < 4; ++i) {
                const int t = tb * 16 + lgrp * 4 + i;
                if (t < TSTEPS)
                    P[((size_t)ks * TSTEPS + t) * NEUR + j] = f2b(acc[jt][tb][i]);
            }
    }
}

// ---------------- K2: reduce bf16 partials -> FF f32 ----------------
__global__ __launch_bounds__(256)
void reduce_ff(const unsigned short* __restrict__ P, float* __restrict__ FF)
{
    const int i = (blockIdx.x * 256 + threadIdx.x) * 8;   // 200 blocks
    float s[8];
#pragma unroll
    for (int n = 0; n < 8; ++n) s[n] = 0.f;
#pragma unroll
    for (int ks = 0; ks < KSPLIT; ++ks) {
        const us8 p = *(const us8*)&P[(size_t)ks * TSTEPS * NEUR + i];
#pragma unroll
        for (int n = 0; n < 8; ++n) s[n] += b2f(p[n]);
    }
    *(float4*)&FF[i]     = make_float4(s[0], s[1], s[2], s[3]);
    *(float4*)&FF[i + 4] = make_float4(s[4], s[5], s[6], s[7]);
}

// ---------------- K3: speculative parallel scan (assumes z == 0) ----------------
__global__ __launch_bounds__(256)
void spec_scan(const float* __restrict__ FF, float* __restrict__ out,
               int* __restrict__ flag)
{
    const int j = blockIdx.x * 256 + threadIdx.x;   // one neuron per thread
    float ff[TSTEPS];                               // full prefetch, static idx
#pragma unroll
    for (int t = 0; t < TSTEPS; ++t) ff[t] = FF[(size_t)t * NEUR + j];

    float v = -70.f, cur = 0.f;
    bool any = false;
#pragma unroll
    for (int t = 0; t < TSTEPS; ++t) {
        const float vd = v + 5.0e-5f * ((-70.f - v) + cur);
        const float id = cur - 1.0e-4f * cur;
        const bool sp = vd > -55.f;
        any |= sp;
        v = sp ? -70.f : vd;
        cur = id + ff[t];                           // no recurrence (speculation)
        out[(size_t)t * NEUR + j] = sp ? 1.f : 0.f;
    }
    if (any) atomicAdd(flag, 1);
}

// ---------------- K4: exact event-driven fallback (only if spikes occurred) ----------------
__global__ __launch_bounds__(1024)
void lif_fallback(const float* __restrict__ FF, const float* __restrict__ wrec,
                  float* __restrict__ out, const int* __restrict__ flag)
{
    if (*flag == 0) return;   // speculation was self-consistent -> out is exact

    const int tid = threadIdx.x;
    __shared__ unsigned short list[2][NEUR];
    __shared__ int cnt[2];

    float v[8], cur[8];
#pragma unroll
    for (int n = 0; n < 8; ++n) { v[n] = -70.0f; cur[n] = 0.0f; }
    if (tid == 0) { cnt[0] = 0; cnt[1] = 0; }

    for (int t = 0; t < TSTEPS; ++t) {
        const int rb = t & 1, wb = rb ^ 1;
        __syncthreads();
        if (tid == 0) cnt[wb] = 0;
        __syncthreads();

        float rec[8];
#pragma unroll
        for (int n = 0; n < 8; ++n) rec[n] = 0.0f;
        const int c = cnt[rb];
        for (int s = 0; s < c; ++s) {
            const int k = list[rb][s];
#pragma unroll
            for (int n = 0; n < 8; ++n)
                rec[n] += wrec[(size_t)(tid + n * 1024) * NEUR + k];
        }

#pragma unroll
        for (int n = 0; n < 8; ++n) {
            const float ff = FF[(size_t)t * NEUR + tid + n * 1024];
            const float vd = v[n] + 5.0e-5f * ((-70.0f - v[n]) + cur[n]);
            const float id = cur[n] - 1.0e-4f * cur[n];
            const bool  sp = vd > -55.0f;
            v[n]   = sp ? -70.0f : vd;
            cur[n] = id + ff + rec[n];
            out[(size_t)t * NEUR + tid + n * 1024] = sp ? 1.0f : 0.0f;
            if (sp) {
                const int pos = atomicAdd(&cnt[wb], 1);
                list[wb][pos] = (unsigned short)(tid + n * 1024);
            }
        }
    }
}

extern "C" void kernel_launch(void* const* d_in, const int* in_sizes, int n_in,
                              void* d_out, int out_size, void* d_ws, size_t ws_size,
                              hipStream_t stream) {
    const float* x     = (const float*)d_in[0];   // [50][8192]
    const float* w_in  = (const float*)d_in[1];   // [8192][8192]
    const float* w_rec = (const float*)d_in[2];   // [8192][8192]
    float* out = (float*)d_out;

    // ws layout (16B-aligned):
    //   FF  f32  [50][8192]          1,638,400 B  @ 0
    //   xb  bf16 [64][8192]          1,048,576 B  @ 1,638,400
    //   P   bf16 [16][50][8192]     13,107,200 B  @ 2,686,976
    //   flag int                            4 B  @ 15,794,176
    float* FF          = (float*)d_ws;
    unsigned short* xb = (unsigned short*)((char*)d_ws + 1638400);
    unsigned short* P  = (unsigned short*)((char*)d_ws + 2686976);
    int* flag          = (int*)((char*)d_ws + 15794176);

    prep        <<<dim3(TPAD * NEUR / 8 / 256),   dim3(256),  0, stream>>>(x, xb, flag);
    ff_gemm_mfma<<<dim3(64 * KSPLIT),             dim3(256),  0, stream>>>(w_in, xb, P);
    reduce_ff   <<<dim3(TSTEPS * NEUR / 8 / 256), dim3(256),  0, stream>>>(P, FF);
    spec_scan   <<<dim3(NEUR / 256),              dim3(256),  0, stream>>>(FF, out, flag);
    lif_fallback<<<dim3(1),                       dim3(1024), 0, stream>>>(FF, w_rec, out, flag);
}